// Round 5
// baseline (152.752 us; speedup 1.0000x reference)
//
#include <hip/hip_runtime.h>
#include <hip/hip_bf16.h>

typedef short short8 __attribute__((ext_vector_type(8)));
typedef unsigned int u32x4 __attribute__((ext_vector_type(4)));
typedef float f32x4 __attribute__((ext_vector_type(4)));
typedef float f32x2 __attribute__((ext_vector_type(2)));

#define SPAT  32768
#define KPROD 27

// ---- prep 1: x [64][32768] f32 -> xt [32768][64] bf16 (128B rows) ----
__global__ void transpose_x_bf16(const float* __restrict__ x, unsigned short* __restrict__ xt) {
    __shared__ float tile[64][65];
    const int t = threadIdx.x;
    const int s0 = blockIdx.x * 64;
    const int lane = t & 63, grp = t >> 6;
#pragma unroll
    for (int r = 0; r < 16; ++r) {
        int c = grp * 16 + r;
        tile[c][lane] = x[c * SPAT + s0 + lane];
    }
    __syncthreads();
#pragma unroll
    for (int r = 0; r < 16; ++r) {
        int srow = grp * 16 + r;
        xt[(s0 + srow) * 64 + lane] = __bfloat16_as_ushort(__float2bfloat16(tile[lane][srow]));
    }
}

// ---- prep 2: weight [o][c][k] f32 -> A-fragments wf[k][i=ot*2+kb][lane][e] bf16 ----
__global__ void prep_w_frag(const float* __restrict__ w, unsigned short* __restrict__ wt) {
    int idx = blockIdx.x * 256 + threadIdx.x;
    if (idx >= KPROD * 4096) return;
    int k = idx >> 12;
    int fid = idx & 4095;
    int i = fid >> 9;                 // ot*2+kb
    int lane = (fid >> 3) & 63;
    int e = fid & 7;
    int ot = i >> 1, kb = i & 1;
    int o = ot * 16 + (lane & 15);
    int c = kb * 32 + (lane >> 4) * 8 + e;
    wt[idx] = __bfloat16_as_ushort(__float2bfloat16(w[(o * 64 + c) * KPROD + k]));
}

// ---- main: 2 waves/block, wave0 = taps 0..13, wave1 = taps 14..26 ----
__global__ __launch_bounds__(128, 4)   // force VGPR <= 128 (4 waves/SIMD)
void dconv3d_wave2(const unsigned short* __restrict__ xt, const unsigned short* __restrict__ wf,
                   const float* __restrict__ offset, const float* __restrict__ mask,
                   float* __restrict__ out) {
    __shared__ float meta_w[2][2][8][24];   // [wid][buf][corner][pl], 2-way max = free
    __shared__ int   meta_o[2][2][8][24];
    __shared__ float red[16][65];           // reduction buffer, padded

    const int t   = threadIdx.x;
    const int wid = t >> 6;
    const int l   = t & 63;
    const int pl  = l & 15;              // my output position (within tile)
    const int g   = l >> 4;              // k-slice group
    const int g16 = g * 16;

    // bijective XCD swizzle (2048 % 8 == 0): neighbor tiles share an XCD L2
    const int nwg = (int)gridDim.x;
    const int cpx = nwg >> 3;
    const int bid = (int)blockIdx.x;
    const int bsw = (bid % 8) * cpx + (bid / 8);

    const int p_base = bsw * 16;
    const int pos = p_base + pl;
    const int ho = pos >> 10, wo = (pos >> 5) & 31, lo = pos & 31;
    const char* xbase = (const char*)xt;
    const int k0 = wid * 14;             // 0 or 14
    const int ntaps = 14 - wid;          // 14 or 13

    f32x4 acc[4] = {};

    auto compute_meta = [&](int k, int buf) {
        float oh = offset[(3 * k + 0) * SPAT + pos];
        float ow = offset[(3 * k + 1) * SPAT + pos];
        float ol = offset[(3 * k + 2) * SPAT + pos];
        float mk = mask[k * SPAT + pos];
        int ki = k / 9, kj = (k / 3) % 3, kk2 = k % 3;
        float chh = oh + (float)(ho - 1 + ki);
        float cww = ow + (float)(wo - 1 + kj);
        float cll = ol + (float)(lo - 1 + kk2);
        float h0f = floorf(chh), w0f = floorf(cww), l0f = floorf(cll);
        float fh = chh - h0f, fw = cww - w0f, fl = cll - l0f;
        int h0 = (int)h0f, w0 = (int)w0f, l0i = (int)l0f;
#pragma unroll
        for (int jj = 0; jj < 2; ++jj) {
            int j = g * 2 + jj;          // this lane owns 2 corners of its p
            int dh = j >> 2, dw = (j >> 1) & 1, dl = j & 1;
            int ih = h0 + dh, iw = w0 + dw, il = l0i + dl;
            float wh = dh ? fh : 1.f - fh;
            float ww = dw ? fw : 1.f - fw;
            float wl = dl ? fl : 1.f - fl;
            bool valid = (unsigned)ih < 32u && (unsigned)iw < 32u && (unsigned)il < 32u;
            float wvv = valid ? wh * ww * wl * mk : 0.f;
            int ihc = min(max(ih, 0), 31);
            int iwc = min(max(iw, 0), 31);
            int ilc = min(max(il, 0), 31);
            int lin = (ihc * 32 + iwc) * 32 + ilc;
            meta_w[wid][buf][j][pl] = wvv;
            meta_o[wid][buf][j][pl] = lin * 128;   // byte offset of bf16 row
        }
    };

    // ---- prologue ----
    compute_meta(k0, 0);
    short8 wfr[8];
#pragma unroll
    for (int i = 0; i < 8; ++i) wfr[i] = *(const short8*)&wf[((size_t)k0 * 8 + i) * 512 + l * 8];

#pragma unroll 1
    for (int kk = 0; kk < ntaps; ++kk) {
        const int k    = k0 + kk;
        const int buf  = kk & 1;
        const int kn   = (kk + 1 < ntaps) ? k + 1 : k;
        const int bufn = buf ^ 1;

        // 1. pull offsets from LDS, issue all 16 gathers for tap k
        u32x4 q0[8], q1[8];
#pragma unroll
        for (int j = 0; j < 8; ++j) {
            const char* rowp = xbase + (meta_o[wid][buf][j][pl] + g16);
            q0[j] = *(const u32x4*)rowp;          // channels g*8..g*8+7
            q1[j] = *(const u32x4*)(rowp + 64);   // channels 32+g*8..
        }

        // 2. overlap: meta for tap k+1
        compute_meta(kn, bufn);

        // 3. consume gathers: trilinear accumulate (float2 -> v_pk_fma_f32)
        f32x2 v0[4] = {}, v1[4] = {};
#pragma unroll
        for (int j = 0; j < 8; ++j) {
            float w = meta_w[wid][buf][j][pl];
            f32x2 w2 = {w, w};
#pragma unroll
            for (int q = 0; q < 4; ++q) {
                unsigned int a = q0[j][q];
                unsigned int b = q1[j][q];
                f32x2 xa = {__uint_as_float(a << 16), __uint_as_float(a & 0xffff0000u)};
                f32x2 xb = {__uint_as_float(b << 16), __uint_as_float(b & 0xffff0000u)};
                v0[q] = __builtin_elementwise_fma(w2, xa, v0[q]);
                v1[q] = __builtin_elementwise_fma(w2, xb, v1[q]);
            }
        }

        // 4. B-fragments (bf16)
        short8 b0, b1;
#pragma unroll
        for (int q = 0; q < 4; ++q) {
            b0[2*q]   = (short)__bfloat16_as_ushort(__float2bfloat16(v0[q].x));
            b0[2*q+1] = (short)__bfloat16_as_ushort(__float2bfloat16(v0[q].y));
            b1[2*q]   = (short)__bfloat16_as_ushort(__float2bfloat16(v1[q].x));
            b1[2*q+1] = (short)__bfloat16_as_ushort(__float2bfloat16(v1[q].y));
        }

        // 5. prefetch W-frags for k+1 (q regs dead here)
        short8 wfn[8];
#pragma unroll
        for (int i = 0; i < 8; ++i) wfn[i] = *(const short8*)&wf[((size_t)kn * 8 + i) * 512 + l * 8];

        // 6. MFMA: 64o x 16p, K=64
        __builtin_amdgcn_s_setprio(1);
#pragma unroll
        for (int ot = 0; ot < 4; ++ot) {
            acc[ot] = __builtin_amdgcn_mfma_f32_16x16x32_bf16(wfr[ot*2+0], b0, acc[ot], 0, 0, 0);
            acc[ot] = __builtin_amdgcn_mfma_f32_16x16x32_bf16(wfr[ot*2+1], b1, acc[ot], 0, 0, 0);
        }
        __builtin_amdgcn_s_setprio(0);

        // 7. rotate W
#pragma unroll
        for (int i = 0; i < 8; ++i) wfr[i] = wfn[i];
    }

    // ---- barrier-ordered 2-way reduction (deterministic) ----
    // D layout: col = lane&15 (p), row = g*4+r (o within 16-block)
    __syncthreads();
    if (wid == 0) {
#pragma unroll
        for (int ot = 0; ot < 4; ++ot)
#pragma unroll
            for (int r = 0; r < 4; ++r)
                red[pl][ot * 16 + g * 4 + r] = acc[ot][r];
    }
    __syncthreads();
    if (wid == 1) {
#pragma unroll
        for (int ot = 0; ot < 4; ++ot)
#pragma unroll
            for (int r = 0; r < 4; ++r)
                red[pl][ot * 16 + g * 4 + r] += acc[ot][r];
    }
    __syncthreads();

    // ---- store: 16-wide p runs per o ----
#pragma unroll
    for (int it = 0; it < 8; ++it) {
        int idx = it * 128 + t;
        int p = idx & 15, o = idx >> 4;
        out[(size_t)o * SPAT + p_base + p] = red[p][o];
    }
}

extern "C" void kernel_launch(void* const* d_in, const int* in_sizes, int n_in,
                              void* d_out, int out_size, void* d_ws, size_t ws_size,
                              hipStream_t stream) {
    const float* x      = (const float*)d_in[0];
    const float* offset = (const float*)d_in[1];
    const float* mask   = (const float*)d_in[2];
    const float* weight = (const float*)d_in[3];
    float* out = (float*)d_out;

    unsigned short* xt  = (unsigned short*)d_ws;                                  // 4 MB
    unsigned short* wtb = (unsigned short*)((char*)d_ws + (size_t)SPAT * 64 * 2); // 216 KB

    hipLaunchKernelGGL(transpose_x_bf16, dim3(SPAT / 64), dim3(256), 0, stream, x, xt);
    hipLaunchKernelGGL(prep_w_frag, dim3((KPROD * 4096 + 255) / 256), dim3(256), 0, stream,
                       weight, wtb);
    hipLaunchKernelGGL(dconv3d_wave2, dim3(SPAT / 16), dim3(128), 0, stream,
                       xt, wtb, offset, mask, out);
}

// Round 6
// 125.210 us; speedup vs baseline: 1.2200x; 1.2200x over previous
//
#include <hip/hip_runtime.h>
#include <hip/hip_bf16.h>

typedef short short8 __attribute__((ext_vector_type(8)));
typedef unsigned int u32x4 __attribute__((ext_vector_type(4)));
typedef float f32x4 __attribute__((ext_vector_type(4)));
typedef float f32x2 __attribute__((ext_vector_type(2)));

#define SPAT  32768
#define KPROD 27

static __device__ __forceinline__ short f2bf(float f) {
    return (short)__bfloat16_as_ushort(__float2bfloat16(f));
}

// ---- prep 1: x [64][32768] f32 -> xt [32768][64] bf16 (128B rows) ----
__global__ void transpose_x_bf16(const float* __restrict__ x, unsigned short* __restrict__ xt) {
    __shared__ float tile[64][65];
    const int t = threadIdx.x;
    const int s0 = blockIdx.x * 64;
    const int lane = t & 63, grp = t >> 6;
#pragma unroll
    for (int r = 0; r < 16; ++r) {
        int c = grp * 16 + r;
        tile[c][lane] = x[c * SPAT + s0 + lane];
    }
    __syncthreads();
#pragma unroll
    for (int r = 0; r < 16; ++r) {
        int srow = grp * 16 + r;
        xt[(s0 + srow) * 64 + lane] = __bfloat16_as_ushort(__float2bfloat16(tile[lane][srow]));
    }
}

// ---- prep 2: weight [o][c][k] f32 -> A-fragments wf[k][i=ot*2+kb][lane][e] bf16 ----
__global__ void prep_w_frag(const float* __restrict__ w, unsigned short* __restrict__ wt) {
    int idx = blockIdx.x * 256 + threadIdx.x;
    if (idx >= KPROD * 4096) return;
    int k = idx >> 12;
    int fid = idx & 4095;
    int i = fid >> 9;                 // ot*2+kb
    int lane = (fid >> 3) & 63;
    int e = fid & 7;
    int ot = i >> 1, kb = i & 1;
    int o = ot * 16 + (lane & 15);
    int c = kb * 32 + (lane >> 4) * 8 + e;
    wt[idx] = __bfloat16_as_ushort(__float2bfloat16(w[(o * 64 + c) * KPROD + k]));
}

// ---- main: 2 waves/block over SAME 16 positions; wave owns half the channels ----
__global__ __launch_bounds__(128)
void dconv3d_csplit(const unsigned short* __restrict__ xt, const unsigned short* __restrict__ wf,
                    const float* __restrict__ offset, const float* __restrict__ mask,
                    float* __restrict__ out) {
    __shared__ float meta_w[2][2][8][24];   // [wid][buf][corner][pl]
    __shared__ int   meta_o[2][2][8][24];
    __shared__ float red[16][65];           // reduction buffer, padded

    const int t    = threadIdx.x;
    const int wid  = t >> 6;             // 0: channels 0-31, 1: channels 32-63
    const int l    = t & 63;
    const int pl   = l & 15;             // my output position (within tile)
    const int g    = l >> 4;             // octet group
    const int goff = wid * 64 + g * 16;  // byte offset within xt row

    // bijective XCD swizzle (2048 % 8 == 0)
    const int nwg = (int)gridDim.x;
    const int cpx = nwg >> 3;
    const int bid = (int)blockIdx.x;
    const int bsw = (bid & 7) * cpx + (bid >> 3);

    const int p_base = bsw * 16;
    const int pos = p_base + pl;
    const int ho = pos >> 10, wo = (pos >> 5) & 31, lo = pos & 31;
    const char* xbase = (const char*)xt;

    f32x4 acc[4] = {};

    auto compute_meta = [&](int k, int buf) {
        float oh = offset[(3 * k + 0) * SPAT + pos];
        float ow = offset[(3 * k + 1) * SPAT + pos];
        float ol = offset[(3 * k + 2) * SPAT + pos];
        float mk = mask[k * SPAT + pos];
        int ki = k / 9, kj = (k / 3) % 3, kk2 = k % 3;
        float chh = oh + (float)(ho - 1 + ki);
        float cww = ow + (float)(wo - 1 + kj);
        float cll = ol + (float)(lo - 1 + kk2);
        float h0f = floorf(chh), w0f = floorf(cww), l0f = floorf(cll);
        float fh = chh - h0f, fw = cww - w0f, fl = cll - l0f;
        int h0 = (int)h0f, w0 = (int)w0f, l0i = (int)l0f;
#pragma unroll
        for (int jj = 0; jj < 2; ++jj) {
            int j = g * 2 + jj;          // this lane owns 2 corners of its p
            int dh = j >> 2, dw = (j >> 1) & 1, dl = j & 1;
            int ih = h0 + dh, iw = w0 + dw, il = l0i + dl;
            float wh = dh ? fh : 1.f - fh;
            float ww = dw ? fw : 1.f - fw;
            float wl = dl ? fl : 1.f - fl;
            bool valid = (unsigned)ih < 32u && (unsigned)iw < 32u && (unsigned)il < 32u;
            float wvv = valid ? wh * ww * wl * mk : 0.f;
            int ihc = min(max(ih, 0), 31);
            int iwc = min(max(iw, 0), 31);
            int ilc = min(max(il, 0), 31);
            int lin = (ihc * 32 + iwc) * 32 + ilc;
            meta_w[wid][buf][j][pl] = wvv;
            meta_o[wid][buf][j][pl] = lin * 128;   // byte offset of bf16 row
        }
    };

    // ---- prologue ----
    compute_meta(0, 0);

#pragma unroll 1
    for (int k = 0; k < KPROD; ++k) {
        const int buf  = k & 1;
        const int kn   = (k + 1 < KPROD) ? k + 1 : k;
        const int bufn = buf ^ 1;

        // 1. W-frags for this tap (4 x b128, sequential L2) — issued first
        short8 wfr[4];
#pragma unroll
        for (int ot = 0; ot < 4; ++ot)
            wfr[ot] = *(const short8*)&wf[((size_t)k * 8 + ot * 2 + wid) * 512 + l * 8];

        // 2. 8 gathers (my channel-octet of each corner row)
        u32x4 q[8];
#pragma unroll
        for (int j = 0; j < 8; ++j)
            q[j] = *(const u32x4*)(xbase + (meta_o[wid][buf][j][pl] + goff));

        // 3. overlap: meta for tap k+1
        compute_meta(kn, bufn);

        // 4. consume gathers (packed fma)
        f32x2 v[4] = {};
#pragma unroll
        for (int j = 0; j < 8; ++j) {
            float w = meta_w[wid][buf][j][pl];
            f32x2 w2 = {w, w};
#pragma unroll
            for (int qd = 0; qd < 4; ++qd) {
                unsigned int a = q[j][qd];
                f32x2 xa = {__uint_as_float(a << 16), __uint_as_float(a & 0xffff0000u)};
                v[qd] = __builtin_elementwise_fma(w2, xa, v[qd]);
            }
        }

        // 5. B-fragment (bf16, K=32)
        short8 b;
#pragma unroll
        for (int qd = 0; qd < 4; ++qd) {
            b[2*qd]   = f2bf(v[qd].x);
            b[2*qd+1] = f2bf(v[qd].y);
        }

        // 6. MFMA: 64o x 16p, K=32 (my channel half)
        __builtin_amdgcn_s_setprio(1);
#pragma unroll
        for (int ot = 0; ot < 4; ++ot)
            acc[ot] = __builtin_amdgcn_mfma_f32_16x16x32_bf16(wfr[ot], b, acc[ot], 0, 0, 0);
        __builtin_amdgcn_s_setprio(0);
    }

    // ---- barrier-ordered 2-way reduction (deterministic) ----
    // D layout: col = lane&15 (p), row = g*4+r (o within 16-block)
    __syncthreads();
    if (wid == 0) {
#pragma unroll
        for (int ot = 0; ot < 4; ++ot)
#pragma unroll
            for (int r = 0; r < 4; ++r)
                red[pl][ot * 16 + g * 4 + r] = acc[ot][r];
    }
    __syncthreads();
    if (wid == 1) {
#pragma unroll
        for (int ot = 0; ot < 4; ++ot)
#pragma unroll
            for (int r = 0; r < 4; ++r)
                red[pl][ot * 16 + g * 4 + r] += acc[ot][r];
    }
    __syncthreads();

    // ---- store: 16-wide p runs per o ----
#pragma unroll
    for (int it = 0; it < 8; ++it) {
        int idx = it * 128 + t;
        int p = idx & 15, o = idx >> 4;
        out[(size_t)o * SPAT + p_base + p] = red[p][o];
    }
}

extern "C" void kernel_launch(void* const* d_in, const int* in_sizes, int n_in,
                              void* d_out, int out_size, void* d_ws, size_t ws_size,
                              hipStream_t stream) {
    const float* x      = (const float*)d_in[0];
    const float* offset = (const float*)d_in[1];
    const float* mask   = (const float*)d_in[2];
    const float* weight = (const float*)d_in[3];
    float* out = (float*)d_out;

    unsigned short* xt  = (unsigned short*)d_ws;                                  // 4 MB
    unsigned short* wtb = (unsigned short*)((char*)d_ws + (size_t)SPAT * 64 * 2); // 216 KB

    hipLaunchKernelGGL(transpose_x_bf16, dim3(SPAT / 64), dim3(256), 0, stream, x, xt);
    hipLaunchKernelGGL(prep_w_frag, dim3((KPROD * 4096 + 255) / 256), dim3(256), 0, stream,
                       weight, wtb);
    hipLaunchKernelGGL(dconv3d_csplit, dim3(SPAT / 16), dim3(128), 0, stream,
                       xt, wtb, offset, mask, out);
}

// Round 7
// 84.526 us; speedup vs baseline: 1.8071x; 1.4813x over previous
//
#include <hip/hip_runtime.h>
#include <hip/hip_bf16.h>

typedef short short8 __attribute__((ext_vector_type(8)));
typedef unsigned int u32x4 __attribute__((ext_vector_type(4)));
typedef float f32x4 __attribute__((ext_vector_type(4)));
typedef float f32x2 __attribute__((ext_vector_type(2)));

#define SPAT  32768
#define KPROD 27

static __device__ __forceinline__ short f2bf(float f) {
    return (short)__bfloat16_as_ushort(__float2bfloat16(f));
}

// ---- prep 1: x [64][32768] f32 -> xt [32768][64] bf16 (128B rows) ----
__global__ void transpose_x_bf16(const float* __restrict__ x, unsigned short* __restrict__ xt) {
    __shared__ float tile[64][65];
    const int t = threadIdx.x;
    const int s0 = blockIdx.x * 64;
    const int lane = t & 63, grp = t >> 6;
#pragma unroll
    for (int r = 0; r < 16; ++r) {
        int c = grp * 16 + r;
        tile[c][lane] = x[c * SPAT + s0 + lane];
    }
    __syncthreads();
#pragma unroll
    for (int r = 0; r < 16; ++r) {
        int srow = grp * 16 + r;
        xt[(s0 + srow) * 64 + lane] = __bfloat16_as_ushort(__float2bfloat16(tile[lane][srow]));
    }
}

// ---- prep 2: weight [o][c][k] f32 -> A-fragments wf[k][i=ot*2+kb][lane][e] bf16 ----
__global__ void prep_w_frag(const float* __restrict__ w, unsigned short* __restrict__ wt) {
    int idx = blockIdx.x * 256 + threadIdx.x;
    if (idx >= KPROD * 4096) return;
    int k = idx >> 12;
    int fid = idx & 4095;
    int i = fid >> 9;                 // ot*2+kb
    int lane = (fid >> 3) & 63;
    int e = fid & 7;
    int ot = i >> 1, kb = i & 1;
    int o = ot * 16 + (lane & 15);
    int c = kb * 32 + (lane >> 4) * 8 + e;
    wt[idx] = __bfloat16_as_ushort(__float2bfloat16(w[(o * 64 + c) * KPROD + k]));
}

// ---- main: 2 waves/block (c-split), quad-coalesced gathers + bpermute bridge ----
__global__ __launch_bounds__(128)
void dconv3d_quad(const unsigned short* __restrict__ xt, const unsigned short* __restrict__ wf,
                  const float* __restrict__ offset, const float* __restrict__ mask,
                  float* __restrict__ out) {
    __shared__ float meta_w[2][2][8][24];   // [wid][buf][corner][pl]
    __shared__ int   meta_o[2][2][8][24];
    __shared__ float red[16][65];

    const int t    = threadIdx.x;
    const int wid  = t >> 6;             // channel half: 0 -> c0-31, 1 -> c32-63
    const int l    = t & 63;
    // MFMA space
    const int pl   = l & 15;             // output position / B col
    const int g    = l >> 4;             // k-slice group
    // gather space (quad-coalesced: lanes 0-3 read one 64B line)
    const int gp   = l >> 2;             // position 0..15
    const int gg   = l & 3;              // 16B chunk within my 64B half
    const int goff = wid * 64 + gg * 16;
    // bpermute index: MFMA-lane l pulls from gather-lane 4*(l&15)+(l>>4)
    const int bpidx = (pl * 4 + g) * 4;

    // bijective XCD swizzle (2048 % 8 == 0)
    const int nwg = (int)gridDim.x;
    const int cpx = nwg >> 3;
    const int bid = (int)blockIdx.x;
    const int bsw = (bid & 7) * cpx + (bid >> 3);

    const int p_base = bsw * 16;
    const int pos = p_base + pl;         // meta space: lane owns position pl, corners g*2,g*2+1
    const int ho = pos >> 10, wo = (pos >> 5) & 31, lo = pos & 31;
    const char* xbase = (const char*)xt;

    f32x4 acc[4] = {};

    auto compute_meta = [&](int k, int buf) {
        float oh = offset[(3 * k + 0) * SPAT + pos];
        float ow = offset[(3 * k + 1) * SPAT + pos];
        float ol = offset[(3 * k + 2) * SPAT + pos];
        float mk = mask[k * SPAT + pos];
        int ki = k / 9, kj = (k / 3) % 3, kk2 = k % 3;
        float chh = oh + (float)(ho - 1 + ki);
        float cww = ow + (float)(wo - 1 + kj);
        float cll = ol + (float)(lo - 1 + kk2);
        float h0f = floorf(chh), w0f = floorf(cww), l0f = floorf(cll);
        float fh = chh - h0f, fw = cww - w0f, fl = cll - l0f;
        int h0 = (int)h0f, w0 = (int)w0f, l0i = (int)l0f;
#pragma unroll
        for (int jj = 0; jj < 2; ++jj) {
            int j = g * 2 + jj;
            int dh = j >> 2, dw = (j >> 1) & 1, dl = j & 1;
            int ih = h0 + dh, iw = w0 + dw, il = l0i + dl;
            float wh = dh ? fh : 1.f - fh;
            float ww = dw ? fw : 1.f - fw;
            float wl = dl ? fl : 1.f - fl;
            bool valid = (unsigned)ih < 32u && (unsigned)iw < 32u && (unsigned)il < 32u;
            float wvv = valid ? wh * ww * wl * mk : 0.f;
            int ihc = min(max(ih, 0), 31);
            int iwc = min(max(iw, 0), 31);
            int ilc = min(max(il, 0), 31);
            int lin = (ihc * 32 + iwc) * 32 + ilc;
            meta_w[wid][buf][j][pl] = wvv;
            meta_o[wid][buf][j][pl] = lin * 128;
        }
    };

    // ---- prologue: meta(0) + gathers(0) ----
    compute_meta(0, 0);
    u32x4 q[8];
#pragma unroll
    for (int j = 0; j < 8; ++j)
        q[j] = *(const u32x4*)(xbase + (meta_o[wid][0][j][gp] + goff));

#pragma unroll 1
    for (int k = 0; k < KPROD; ++k) {
        const int buf  = k & 1;
        const int bufn = buf ^ 1;

        // 1. meta for tap k+1 (global loads + VALU, writes other LDS buf)
        if (k + 1 < KPROD) compute_meta(k + 1, bufn);

        // 2. W-frags for this tap (4 x b128, coalesced)
        short8 wfr[4];
#pragma unroll
        for (int ot = 0; ot < 4; ++ot)
            wfr[ot] = *(const short8*)&wf[((size_t)k * 8 + ot * 2 + wid) * 512 + l * 8];

        // 3. consume gathers (gather space: position gp, channels gg*8..gg*8+7)
        f32x2 v[4] = {};
#pragma unroll
        for (int j = 0; j < 8; ++j) {
            float w = meta_w[wid][buf][j][gp];
            f32x2 w2 = {w, w};
#pragma unroll
            for (int qd = 0; qd < 4; ++qd) {
                unsigned int a = q[j][qd];
                f32x2 xa = {__uint_as_float(a << 16), __uint_as_float(a & 0xffff0000u)};
                v[qd] = __builtin_elementwise_fma(w2, xa, v[qd]);
            }
        }

        // 4. B-fragment in gather space -> bf16
        union { short8 s; u32x4 u; } bg;
#pragma unroll
        for (int qd = 0; qd < 4; ++qd) {
            bg.s[2*qd]   = f2bf(v[qd].x);
            bg.s[2*qd+1] = f2bf(v[qd].y);
        }

        // 5. issue gathers for tap k+1 (q dead; fly under MFMA + next meta/W)
        if (k + 1 < KPROD) {
#pragma unroll
            for (int j = 0; j < 8; ++j)
                q[j] = *(const u32x4*)(xbase + (meta_o[wid][bufn][j][gp] + goff));
        }

        // 6. bridge to MFMA space: pure lane permutation (4 x ds_bpermute)
        union { u32x4 u; short8 s; } bm;
#pragma unroll
        for (int d = 0; d < 4; ++d)
            bm.u[d] = (unsigned)__builtin_amdgcn_ds_bpermute(bpidx, (int)bg.u[d]);

        // 7. MFMA: 64o x 16p, K=32 (my channel half)
        __builtin_amdgcn_s_setprio(1);
#pragma unroll
        for (int ot = 0; ot < 4; ++ot)
            acc[ot] = __builtin_amdgcn_mfma_f32_16x16x32_bf16(wfr[ot], bm.s, acc[ot], 0, 0, 0);
        __builtin_amdgcn_s_setprio(0);
    }

    // ---- barrier-ordered 2-way reduction (deterministic) ----
    __syncthreads();
    if (wid == 0) {
#pragma unroll
        for (int ot = 0; ot < 4; ++ot)
#pragma unroll
            for (int r = 0; r < 4; ++r)
                red[pl][ot * 16 + g * 4 + r] = acc[ot][r];
    }
    __syncthreads();
    if (wid == 1) {
#pragma unroll
        for (int ot = 0; ot < 4; ++ot)
#pragma unroll
            for (int r = 0; r < 4; ++r)
                red[pl][ot * 16 + g * 4 + r] += acc[ot][r];
    }
    __syncthreads();

    // ---- store: 16-wide p runs per o ----
#pragma unroll
    for (int it = 0; it < 8; ++it) {
        int idx = it * 128 + t;
        int p = idx & 15, o = idx >> 4;
        out[(size_t)o * SPAT + p_base + p] = red[p][o];
    }
}

extern "C" void kernel_launch(void* const* d_in, const int* in_sizes, int n_in,
                              void* d_out, int out_size, void* d_ws, size_t ws_size,
                              hipStream_t stream) {
    const float* x      = (const float*)d_in[0];
    const float* offset = (const float*)d_in[1];
    const float* mask   = (const float*)d_in[2];
    const float* weight = (const float*)d_in[3];
    float* out = (float*)d_out;

    unsigned short* xt  = (unsigned short*)d_ws;                                  // 4 MB
    unsigned short* wtb = (unsigned short*)((char*)d_ws + (size_t)SPAT * 64 * 2); // 216 KB

    hipLaunchKernelGGL(transpose_x_bf16, dim3(SPAT / 64), dim3(256), 0, stream, x, xt);
    hipLaunchKernelGGL(prep_w_frag, dim3((KPROD * 4096 + 255) / 256), dim3(256), 0, stream,
                       weight, wtb);
    hipLaunchKernelGGL(dconv3d_quad, dim3(SPAT / 16), dim3(128), 0, stream,
                       xt, wtb, offset, mask, out);
}

// Round 9
// 83.915 us; speedup vs baseline: 1.8203x; 1.0073x over previous
//
#include <hip/hip_runtime.h>
#include <hip/hip_bf16.h>

typedef short short8 __attribute__((ext_vector_type(8)));
typedef unsigned int u32x4 __attribute__((ext_vector_type(4)));
typedef float f32x4 __attribute__((ext_vector_type(4)));
typedef float f32x2 __attribute__((ext_vector_type(2)));

#define SPAT  32768
#define KPROD 27

static __device__ __forceinline__ short f2bf(float f) {
    return (short)__bfloat16_as_ushort(__float2bfloat16(f));
}

// ---- prep 1: x [64][32768] f32 -> xt [32768][64] bf16 (128B rows) ----
__global__ void transpose_x_bf16(const float* __restrict__ x, unsigned short* __restrict__ xt) {
    __shared__ float tile[64][65];
    const int t = threadIdx.x;
    const int s0 = blockIdx.x * 64;
    const int lane = t & 63, grp = t >> 6;
#pragma unroll
    for (int r = 0; r < 16; ++r) {
        int c = grp * 16 + r;
        tile[c][lane] = x[c * SPAT + s0 + lane];
    }
    __syncthreads();
#pragma unroll
    for (int r = 0; r < 16; ++r) {
        int srow = grp * 16 + r;
        xt[(s0 + srow) * 64 + lane] = __bfloat16_as_ushort(__float2bfloat16(tile[lane][srow]));
    }
}

// ---- prep 2: weight [o][c][k] f32 -> A-fragments wf[k][i=ot*2+kb][lane][e] bf16 ----
__global__ void prep_w_frag(const float* __restrict__ w, unsigned short* __restrict__ wt) {
    int idx = blockIdx.x * 256 + threadIdx.x;
    if (idx >= KPROD * 4096) return;
    int k = idx >> 12;
    int fid = idx & 4095;
    int i = fid >> 9;                 // ot*2+kb
    int lane = (fid >> 3) & 63;
    int e = fid & 7;
    int ot = i >> 1, kb = i & 1;
    int o = ot * 16 + (lane & 15);
    int c = kb * 32 + (lane >> 4) * 8 + e;
    wt[idx] = __bfloat16_as_ushort(__float2bfloat16(w[(o * 64 + c) * KPROD + k]));
}

// ---- main: c-split 2 waves, quad-coalesced gathers, depth-2 off/mask prefetch ----
__global__ __launch_bounds__(128)
void dconv3d_pipe(const unsigned short* __restrict__ xt, const unsigned short* __restrict__ wf,
                  const float* __restrict__ offset, const float* __restrict__ mask,
                  float* __restrict__ out) {
    __shared__ f32x2 meta[2][2][8][17];   // [wid][buf][corner][pos] = {w, off_bytes}
    __shared__ float red[16][65];

    const int t    = threadIdx.x;
    const int wid  = t >> 6;             // channel half
    const int l    = t & 63;
    // MFMA space
    const int pl   = l & 15;
    const int g    = l >> 4;
    const int dh   = g >> 1, dw = g & 1; // my corner-pair (dl = 0,1)
    // gather space
    const int gp   = l >> 2;
    const int gg   = l & 3;
    const int goff = wid * 64 + gg * 16;
    const int bpidx = (pl * 4 + g) * 4;  // MFMA-lane pulls gather-lane 4*pl+g

    // bijective XCD swizzle (2048 % 8 == 0)
    const int nwg = (int)gridDim.x;
    const int cpx = nwg >> 3;
    const int bid = (int)blockIdx.x;
    const int bsw = (bid & 7) * cpx + (bid >> 3);

    const int p_base = bsw * 16;
    const int pos = p_base + pl;
    const int ho = pos >> 10, wo = (pos >> 5) & 31, lo = pos & 31;
    const float fho = (float)(ho - 1), fwo = (float)(wo - 1), flo = (float)(lo - 1);
    const char* xbase = (const char*)xt;

    f32x4 acc[4] = {};

    auto load_off = [&](int k) -> f32x4 {
        f32x4 r;
        r.x = offset[(3 * k + 0) * SPAT + pos];
        r.y = offset[(3 * k + 1) * SPAT + pos];
        r.z = offset[(3 * k + 2) * SPAT + pos];
        r.w = mask[k * SPAT + pos];
        return r;
    };

    auto compute_meta = [&](int k, int buf, f32x4 om) {
        int ki = k / 9, kj = (k / 3) % 3, kk2 = k % 3;
        float chh = om.x + (fho + (float)ki);
        float cww = om.y + (fwo + (float)kj);
        float cll = om.z + (flo + (float)kk2);
        float h0f = floorf(chh), w0f = floorf(cww), l0f = floorf(cll);
        float fh = chh - h0f, fw = cww - w0f, fl = cll - l0f;
        int h0 = (int)h0f, w0 = (int)w0f, l0i = (int)l0f;
        int ih = h0 + dh, iw = w0 + dw;
        float wh = dh ? fh : 1.f - fh;
        float ww = dw ? fw : 1.f - fw;
        float whwm = wh * ww * om.w;
        float w1v = whwm * fl;          // corner dl=1
        float w0v = whwm - w1v;         // corner dl=0
        bool vhw = ((unsigned)ih < 32u) && ((unsigned)iw < 32u);
        bool v0 = vhw && ((unsigned)l0i < 32u);
        bool v1 = vhw && ((unsigned)(l0i + 1) < 32u);
        w0v = v0 ? w0v : 0.f;
        w1v = v1 ? w1v : 0.f;
        int ihc = min(max(ih, 0), 31), iwc = min(max(iw, 0), 31);
        int l0c = min(max(l0i, 0), 31);
        int l1c = min(max(l0i + 1, 0), 31);   // FIX: clamp dl=1 coord independently
        int base2 = (ihc * 32 + iwc) * 32;
        f32x2 m0, m1;
        m0.x = w0v; m0.y = __int_as_float((base2 + l0c) << 7);
        m1.x = w1v; m1.y = __int_as_float((base2 + l1c) << 7);
        meta[wid][buf][2 * g][pl]     = m0;
        meta[wid][buf][2 * g + 1][pl] = m1;
    };

    // ---- prologue: meta(0) computed, off(1) in flight, q(0) issued ----
    f32x4 offA = load_off(0);
    compute_meta(0, 0, offA);
    offA = load_off(1);
    float mw[8]; int mo[8];
#pragma unroll
    for (int j = 0; j < 8; ++j) {
        f32x2 md = meta[wid][0][j][gp];
        mw[j] = md.x; mo[j] = __float_as_int(md.y);
    }
    u32x4 q[8];
#pragma unroll
    for (int j = 0; j < 8; ++j)
        q[j] = *(const u32x4*)(xbase + (mo[j] + goff));

#pragma unroll 1
    for (int k = 0; k < KPROD; ++k) {
        const int buf  = k & 1;
        const int bufn = buf ^ 1;

        // 1. issue off/mask loads for tap k+2 (register prefetch, depth 2)
        f32x4 offB;
        if (k + 2 < KPROD) offB = load_off(k + 2);

        // 2. meta for tap k+1 from registers (no global latency in chain)
        if (k + 1 < KPROD) compute_meta(k + 1, bufn, offA);

        // 3. W-frags for this tap (4 x b128, coalesced; used at step 7)
        short8 wfr[4];
#pragma unroll
        for (int ot = 0; ot < 4; ++ot)
            wfr[ot] = *(const short8*)&wf[((size_t)k * 8 + ot * 2 + wid) * 512 + l * 8];

        // 4. consume gathers (gather space), weights from registers
        f32x2 v[4] = {};
#pragma unroll
        for (int j = 0; j < 8; ++j) {
            f32x2 w2 = {mw[j], mw[j]};
#pragma unroll
            for (int qd = 0; qd < 4; ++qd) {
                unsigned int a = q[j][qd];
                f32x2 xa = {__uint_as_float(a << 16), __uint_as_float(a & 0xffff0000u)};
                v[qd] = __builtin_elementwise_fma(w2, xa, v[qd]);
            }
        }
        union { short8 s; u32x4 u; } bg;
#pragma unroll
        for (int qd = 0; qd < 4; ++qd) {
            bg.s[2 * qd]     = f2bf(v[qd].x);
            bg.s[2 * qd + 1] = f2bf(v[qd].y);
        }

        // 5. pull meta(k+1) {w,off} and issue gathers for k+1 (q dead)
        if (k + 1 < KPROD) {
#pragma unroll
            for (int j = 0; j < 8; ++j) {
                f32x2 md = meta[wid][bufn][j][gp];
                mw[j] = md.x; mo[j] = __float_as_int(md.y);
            }
#pragma unroll
            for (int j = 0; j < 8; ++j)
                q[j] = *(const u32x4*)(xbase + (mo[j] + goff));
        }

        // 6. bridge to MFMA space (pure lane permutation)
        union { u32x4 u; short8 s; } bm;
#pragma unroll
        for (int d = 0; d < 4; ++d)
            bm.u[d] = (unsigned)__builtin_amdgcn_ds_bpermute(bpidx, (int)bg.u[d]);

        // 7. MFMA: 64o x 16p, K=32 (my channel half)
        __builtin_amdgcn_s_setprio(1);
#pragma unroll
        for (int ot = 0; ot < 4; ++ot)
            acc[ot] = __builtin_amdgcn_mfma_f32_16x16x32_bf16(wfr[ot], bm.s, acc[ot], 0, 0, 0);
        __builtin_amdgcn_s_setprio(0);

        // 8. rotate off/mask prefetch registers
        offA = offB;
    }

    // ---- barrier-ordered 2-way reduction (deterministic) ----
    __syncthreads();
    if (wid == 0) {
#pragma unroll
        for (int ot = 0; ot < 4; ++ot)
#pragma unroll
            for (int r = 0; r < 4; ++r)
                red[pl][ot * 16 + g * 4 + r] = acc[ot][r];
    }
    __syncthreads();
    if (wid == 1) {
#pragma unroll
        for (int ot = 0; ot < 4; ++ot)
#pragma unroll
            for (int r = 0; r < 4; ++r)
                red[pl][ot * 16 + g * 4 + r] += acc[ot][r];
    }
    __syncthreads();

    // ---- store: 16-wide p runs per o ----
#pragma unroll
    for (int it = 0; it < 8; ++it) {
        int idx = it * 128 + t;
        int p = idx & 15, o = idx >> 4;
        out[(size_t)o * SPAT + p_base + p] = red[p][o];
    }
}

extern "C" void kernel_launch(void* const* d_in, const int* in_sizes, int n_in,
                              void* d_out, int out_size, void* d_ws, size_t ws_size,
                              hipStream_t stream) {
    const float* x      = (const float*)d_in[0];
    const float* offset = (const float*)d_in[1];
    const float* mask   = (const float*)d_in[2];
    const float* weight = (const float*)d_in[3];
    float* out = (float*)d_out;

    unsigned short* xt  = (unsigned short*)d_ws;                                  // 4 MB
    unsigned short* wtb = (unsigned short*)((char*)d_ws + (size_t)SPAT * 64 * 2); // 216 KB

    hipLaunchKernelGGL(transpose_x_bf16, dim3(SPAT / 64), dim3(256), 0, stream, x, xt);
    hipLaunchKernelGGL(prep_w_frag, dim3((KPROD * 4096 + 255) / 256), dim3(256), 0, stream,
                       weight, wtb);
    hipLaunchKernelGGL(dconv3d_pipe, dim3(SPAT / 16), dim3(128), 0, stream,
                       xt, wtb, offset, mask, out);
}